// Round 19
// baseline (101.746 us; speedup 1.0000x reference)
//
#include <hip/hip_runtime.h>

// UniformBottomUpHTMM: T=64 trees, depth 10 (N1=2047 heap), C=16, M=64,
// G=16. r30: REGISTER-RESIDENT tail. r29 neutral (95.2->94.7); remaining
// serial structure = the 1-wave 6-level tail, each level a dependent
// ~240cy LDS round-trip + lgkmcnt drain + wave_barrier.
// Fix: after the first tail level (cnt2=32, fed from L6's LDS output),
// lane (half h, node n) keeps its 8 normalized rows in rr[0..7]. Child
// rows for the next level come via __shfl(rr[slot], 32*(j/8)+2n+c) -- 32
// shuffles/level on the VALU pipe (no memory latency, no barriers)
// replacing 16 LDS reads + 8 stores + drain per level.
// Correctness: compute UNGUARDED (all 64 lanes run every level) so shfl
// sources are always in EXEC (ds_bpermute from inactive lanes is not
// guaranteed); garbage lanes (n>=cnt2) are provably never sourced (next
// level sources nodes < cnt2); ll add stays guarded. 0.5f*(a+b) keeps
// the exact operand order of the old 0.5f*(c.x+c.y) -> bit-exact.
// Tripwires: absmax!=0 => revert tail to LDS; VGPR>128/WRITE>>4KB => spill.
// Structure: 1024 independent blocks, one (t,g) each, no workspace/atomics.

#define C_DIM 16
#define M_DIM 64
#define G_DIM 16
#define T_TREES 64
#define N1 2047
#define NBLOCKS (T_TREES * G_DIM)   // 1024
#define BTS 20                      // padded row stride (floats) for xv-tables

__device__ __forceinline__ float4 f4add(float4 a, float4 b) {
    return make_float4(a.x + b.x, a.y + b.y, a.z + b.z, a.w + b.w);
}
__device__ __forceinline__ float4 f4mul(float4 a, float4 b) {
    return make_float4(a.x * b.x, a.y * b.y, a.z * b.z, a.w * b.w);
}
__device__ __forceinline__ float4 f4fma(float4 a, float4 b, float4 c) {
    return make_float4(fmaf(a.x, b.x, c.x), fmaf(a.y, b.y, c.y),
                       fmaf(a.z, b.z, c.z), fmaf(a.w, b.w, c.w));
}
__device__ __forceinline__ float hsum4(float4 a) { return a.x + a.y + a.z + a.w; }

// Full 16x16 matvec (leaf L8 only): unfenced (r29) -- loads may pipeline.
__device__ __forceinline__ float matvec_bt(const float* __restrict__ A,
                                           const float* __restrict__ bt,
                                           const float4 sv[4], float4 bp[4])
{
    float nu = 0.f;
    #pragma unroll
    for (int q = 0; q < 4; ++q) {
        const float4 b4 = *(const float4*)(bt + 4 * q);
        float tr[4];
        #pragma unroll
        for (int r = 0; r < 4; ++r) {
            const float4* ar = (const float4*)(A + (4 * q + r) * 16);
            float4 m = f4mul(ar[0], sv[0]);
            m = f4fma(ar[1], sv[1], m);
            m = f4fma(ar[2], sv[2], m);
            m = f4fma(ar[3], sv[3], m);
            tr[r] = hsum4(m);
        }
        bp[q] = f4mul(make_float4(tr[0], tr[1], tr[2], tr[3]), b4);
        nu += hsum4(bp[q]);
    }
    return nu;
}

// Half-matvec for the hi/lo split phases: rows r0..r0+7, unfenced.
__device__ __forceinline__ void halfmv(const float* __restrict__ A,
                                       const float* __restrict__ bt,
                                       const float4 sv[4], const int r0,
                                       float4& bpA, float4& bpB,
                                       float& hA, float& hB)
{
    float trA[4], trB[4];
    #pragma unroll
    for (int r = 0; r < 4; ++r) {
        const float4* ar = (const float4*)(A + (r0 + r) * 16);
        float4 m = f4mul(ar[0], sv[0]);
        m = f4fma(ar[1], sv[1], m);
        m = f4fma(ar[2], sv[2], m);
        m = f4fma(ar[3], sv[3], m);
        trA[r] = hsum4(m);
    }
    #pragma unroll
    for (int r = 0; r < 4; ++r) {
        const float4* ar = (const float4*)(A + (r0 + 4 + r) * 16);
        float4 m = f4mul(ar[0], sv[0]);
        m = f4fma(ar[1], sv[1], m);
        m = f4fma(ar[2], sv[2], m);
        m = f4fma(ar[3], sv[3], m);
        trB[r] = hsum4(m);
    }
    bpA = f4mul(make_float4(trA[0], trA[1], trA[2], trA[3]),
                *(const float4*)(bt + r0));
    bpB = f4mul(make_float4(trB[0], trB[1], trB[2], trB[3]),
                *(const float4*)(bt + r0 + 4));
    hA = hsum4(bpA);
    hB = hsum4(bpB);
}

__global__ __launch_bounds__(256, 1) void htmm_fused(
    const int* __restrict__ x,
    const int* __restrict__ inv_map,
    const float* __restrict__ lA,
    const float* __restrict__ lB,
    const float* __restrict__ lPi,
    float* __restrict__ out)
{
    const int bid = blockIdx.x;           // 1024 blocks: g = bid>>6, t = bid&63
    const int tid = threadIdx.x;
    const int g = bid >> 6;
    const int t = bid & (T_TREES - 1);

    // ---- manual LDS layout (r21 diet): 32768 B ----
    __shared__ __align__(16) unsigned char smem[32768];
    float* const sA   = (float*)(smem);            //     0 .. 1024   A row-major
    float* const sBt  = (float*)(smem + 1024);     //  1024 .. 6144   Bt[xv][c] stride 20
    float* const sPB  = (float*)(smem + 6144);     //  6144 .. 11264  tA[x]=A·PB[x] (leaf-phase only)
    float* const sLog = (float*)(smem + 11264);    // 11264 .. 11520  (dead after leaf)
    float* const sPi  = (float*)(smem + 11520);    // 11520 .. 11584  (dead after tables)
    float* const buf1 = (float*)(smem + 6144);     // UNION: live from L7 on (8192B)
    unsigned char* const xs = smem + 14336;        // 14336 .. 16384
    float* const buf0 = (float*)(smem + 16384);    // 16384 .. 32768
    float* const wsum = (float*)(smem + 32752);    // buf0 row15 col252-255 (tail-unused)

    // ---- tree symbols (coalesced; 16 same-tree blocks share L2) ----
    {
        const int base = t * N1;
        for (int i = tid; i < N1; i += 256)
            xs[i] = (unsigned char)x[inv_map[base + i]];
    }
    // ---- A softmax (over i within 16-lane segments) ----
    {
        int j = tid >> 4, i = tid & 15;
        float v = lA[(i * C_DIM + j) * G_DIM + g];
        float mx = v;
        #pragma unroll
        for (int m = 1; m < 16; m <<= 1) mx = fmaxf(mx, __shfl_xor(mx, m, 16));
        float e = __expf(v - mx);
        float s = e;
        #pragma unroll
        for (int m = 1; m < 16; m <<= 1) s += __shfl_xor(s, m, 16);
        sA[i * C_DIM + j] = e / s;
    }
    // ---- B softmax (over m), written TRANSPOSED: sBt[xv*BTS + c] ----
    {
        int c = tid >> 4, l16 = tid & 15;
        float e0 = lB[(c * M_DIM + l16 +  0) * G_DIM + g];
        float e1 = lB[(c * M_DIM + l16 + 16) * G_DIM + g];
        float e2 = lB[(c * M_DIM + l16 + 32) * G_DIM + g];
        float e3 = lB[(c * M_DIM + l16 + 48) * G_DIM + g];
        float mx = fmaxf(fmaxf(e0, e1), fmaxf(e2, e3));
        #pragma unroll
        for (int m = 1; m < 16; m <<= 1) mx = fmaxf(mx, __shfl_xor(mx, m, 16));
        e0 = __expf(e0 - mx); e1 = __expf(e1 - mx);
        e2 = __expf(e2 - mx); e3 = __expf(e3 - mx);
        float s = e0 + e1 + e2 + e3;
        #pragma unroll
        for (int m = 1; m < 16; m <<= 1) s += __shfl_xor(s, m, 16);
        float inv = 1.f / s;
        sBt[(l16 +  0) * BTS + c] = e0 * inv;
        sBt[(l16 + 16) * BTS + c] = e1 * inv;
        sBt[(l16 + 32) * BTS + c] = e2 * inv;
        sBt[(l16 + 48) * BTS + c] = e3 * inv;
    }
    if (tid < C_DIM) {  // Pi softmax
        float v = lPi[tid * G_DIM + g];
        float mx = v;
        #pragma unroll
        for (int m = 1; m < 16; m <<= 1) mx = fmaxf(mx, __shfl_xor(mx, m, 16));
        float e = __expf(v - mx);
        float s = e;
        #pragma unroll
        for (int m = 1; m < 16; m <<= 1) s += __shfl_xor(s, m, 16);
        sPi[tid] = e / s;
    }
    __syncthreads();

    // ---- leaf tables + LINEARITY fold on 2 WAVES, hi/lo split (r29) ----
    if (tid < 128) {
        const int w    = tid >> 6;            // wave 0..1
        const int half = (tid >> 5) & 1;      // 0: rows 0-7, 1: rows 8-15
        const int xv   = 32 * w + (tid & 31); // symbol 0..63
        float pb[16]; float nu = 0.f;
        #pragma unroll
        for (int k = 0; k < 16; ++k) {
            pb[k] = sPi[k] * sBt[xv * BTS + k];
            nu += pb[k];
        }
        const float inv = 0.5f / nu;
        #pragma unroll
        for (int k = 0; k < 16; ++k) pb[k] *= inv;
        if (half == 0) sLog[xv] = __logf(nu);
        const float4 pv0 = make_float4(pb[0],  pb[1],  pb[2],  pb[3]);
        const float4 pv1 = make_float4(pb[4],  pb[5],  pb[6],  pb[7]);
        const float4 pv2 = make_float4(pb[8],  pb[9],  pb[10], pb[11]);
        const float4 pv3 = make_float4(pb[12], pb[13], pb[14], pb[15]);
        const int r0 = half * 8;
        float ta[8];
        #pragma unroll
        for (int i = 0; i < 8; ++i) {
            const float4* ar = (const float4*)(sA + (r0 + i) * 16);
            float4 m = f4mul(ar[0], pv0);
            m = f4fma(ar[1], pv1, m);
            m = f4fma(ar[2], pv2, m);
            m = f4fma(ar[3], pv3, m);
            ta[i] = hsum4(m);
        }
        *(float4*)(&sPB[xv * BTS + r0])     = make_float4(ta[0], ta[1], ta[2], ta[3]);
        *(float4*)(&sPB[xv * BTS + r0 + 4]) = make_float4(ta[4], ta[5], ta[6], ta[7]);
    }
    __syncthreads();

    float ll = 0.f;

    // ---- fused leaves+L9 (TABLE, interleaved) + L8 matvec ----
    {
        const int idx = tid;
        const int p8  = 255 + idx;
        const int xl0 = xs[4 * p8 + 3], xr0 = xs[4 * p8 + 4];
        const int xl1 = xs[4 * p8 + 5], xr1 = xs[4 * p8 + 6];
        const int xva = xs[2 * p8 + 1], xvb = xs[2 * p8 + 2];
        const int xv8 = xs[p8];

        const float* tl0 = &sPB[xl0 * BTS];
        const float* tr0 = &sPB[xr0 * BTS];
        const float* tl1 = &sPB[xl1 * BTS];
        const float* tr1 = &sPB[xr1 * BTS];
        const float* bta = &sBt[xva * BTS];
        const float* btb = &sBt[xvb * BTS];

        float4 bpa[4], bpb[4];
        float nua = 0.f, nub = 0.f;
        #pragma unroll
        for (int q = 0; q < 4; ++q) {
            float4 tva = f4add(*(const float4*)(tl0 + 4*q),
                               *(const float4*)(tr0 + 4*q));
            float4 tvb = f4add(*(const float4*)(tl1 + 4*q),
                               *(const float4*)(tr1 + 4*q));
            bpa[q] = f4mul(tva, *(const float4*)(bta + 4*q));
            bpb[q] = f4mul(tvb, *(const float4*)(btb + 4*q));
            nua += hsum4(bpa[q]);
            nub += hsum4(bpb[q]);
        }
        const float ia = 0.5f / nua, ib = 0.5f / nub;
        float4 s8v[4];
        #pragma unroll
        for (int q = 0; q < 4; ++q)
            s8v[q] = f4add(f4mul(bpa[q], make_float4(ia, ia, ia, ia)),
                           f4mul(bpb[q], make_float4(ib, ib, ib, ib)));

        float4 bp[4];
        const float nu8 = matvec_bt(sA, &sBt[xv8 * BTS], s8v, bp);
        ll += sLog[xl0] + sLog[xr0] + sLog[xl1] + sLog[xr1]
            + __logf(nua * nub * nu8);
        const float inv = 1.f / nu8;
        #pragma unroll
        for (int q = 0; q < 4; ++q) {
            buf0[(4*q + 0) * 256 + idx] = bp[q].x * inv;
            buf0[(4*q + 1) * 256 + idx] = bp[q].y * inv;
            buf0[(4*q + 2) * 256 + idx] = bp[q].z * inv;
            buf0[(4*q + 3) * 256 + idx] = bp[q].w * inv;
        }
    }
    __syncthreads();

    // ---- L7: 128 nodes on ALL 4 waves, hi/lo split (unfenced) ----
    {
        const int w    = tid >> 6;            // wave 0..3
        const int half = (tid >> 5) & 1;      // 0: rows 0-7, 1: rows 8-15
        const int n    = 32 * w + (tid & 31); // node 0..127
        float4 sv[4];
        #pragma unroll
        for (int q = 0; q < 4; ++q) {
            float2 c0 = *(const float2*)(&buf0[(4*q + 0) * 256 + 2 * n]);
            float2 c1 = *(const float2*)(&buf0[(4*q + 1) * 256 + 2 * n]);
            float2 c2 = *(const float2*)(&buf0[(4*q + 2) * 256 + 2 * n]);
            float2 c3 = *(const float2*)(&buf0[(4*q + 3) * 256 + 2 * n]);
            sv[q] = make_float4(0.5f * (c0.x + c0.y), 0.5f * (c1.x + c1.y),
                                0.5f * (c2.x + c2.y), 0.5f * (c3.x + c3.y));
        }
        const int xv = xs[127 + n];
        const int r0 = half * 8;
        float4 bpA, bpB; float hA, hB;
        halfmv(sA, &sBt[xv * BTS], sv, r0, bpA, bpB, hA, hB);
        const float pA = __shfl_xor(hA, 32, 64);
        const float pB = __shfl_xor(hB, 32, 64);
        const float nu = half ? (((pA + pB) + hA) + hB)
                              : (((hA + hB) + pA) + pB);
        if (half == 0) ll += __logf(nu);
        const float inv = 1.f / nu;
        buf1[(r0 + 0) * 128 + n] = bpA.x * inv;
        buf1[(r0 + 1) * 128 + n] = bpA.y * inv;
        buf1[(r0 + 2) * 128 + n] = bpA.z * inv;
        buf1[(r0 + 3) * 128 + n] = bpA.w * inv;
        buf1[(r0 + 4) * 128 + n] = bpB.x * inv;
        buf1[(r0 + 5) * 128 + n] = bpB.y * inv;
        buf1[(r0 + 6) * 128 + n] = bpB.z * inv;
        buf1[(r0 + 7) * 128 + n] = bpB.w * inv;
    }
    __syncthreads();

    // ---- L6: 64 nodes on 2 waves, hi/lo split (unfenced) ----
    if (tid < 128) {
        const int w    = tid >> 6;            // wave 0..1
        const int half = (tid >> 5) & 1;
        const int n    = 32 * w + (tid & 31); // node 0..63
        float4 sv[4];
        #pragma unroll
        for (int q = 0; q < 4; ++q) {
            float2 c0 = *(const float2*)(&buf1[(4*q + 0) * 128 + 2 * n]);
            float2 c1 = *(const float2*)(&buf1[(4*q + 1) * 128 + 2 * n]);
            float2 c2 = *(const float2*)(&buf1[(4*q + 2) * 128 + 2 * n]);
            float2 c3 = *(const float2*)(&buf1[(4*q + 3) * 128 + 2 * n]);
            sv[q] = make_float4(0.5f * (c0.x + c0.y), 0.5f * (c1.x + c1.y),
                                0.5f * (c2.x + c2.y), 0.5f * (c3.x + c3.y));
        }
        const int xv = xs[63 + n];
        const int r0 = half * 8;
        float4 bpA, bpB; float hA, hB;
        halfmv(sA, &sBt[xv * BTS], sv, r0, bpA, bpB, hA, hB);
        const float pA = __shfl_xor(hA, 32, 64);
        const float pB = __shfl_xor(hB, 32, 64);
        const float nu = half ? (((pA + pB) + hA) + hB)
                              : (((hA + hB) + pA) + pB);
        if (half == 0) ll += __logf(nu);
        const float inv = 1.f / nu;
        buf0[(r0 + 0) * 256 + n] = bpA.x * inv;
        buf0[(r0 + 1) * 256 + n] = bpA.y * inv;
        buf0[(r0 + 2) * 256 + n] = bpA.z * inv;
        buf0[(r0 + 3) * 256 + n] = bpA.w * inv;
        buf0[(r0 + 4) * 256 + n] = bpB.x * inv;
        buf0[(r0 + 5) * 256 + n] = bpB.y * inv;
        buf0[(r0 + 6) * 256 + n] = bpB.z * inv;
        buf0[(r0 + 7) * 256 + n] = bpB.w * inv;
    }
    __syncthreads();

    // ---- tail L5..L0 (cnt2=32..1): wave 0, REGISTER-RESIDENT ----
    if (tid < 64) {
        const int half = tid >> 5;            // 0: rows 0-7, 1: rows 8-15
        const int n0   = tid & 31;            // node index
        const int r0   = half * 8;
        float rr[8];                          // my 8 normalized rows of node n0

        // cnt2=32: sv from LDS (L6 output, 64 nodes in buf0 stride 256)
        {
            float4 sv[4];
            #pragma unroll
            for (int q = 0; q < 4; ++q) {
                float2 c0 = *(const float2*)(&buf0[(4*q + 0) * 256 + 2 * n0]);
                float2 c1 = *(const float2*)(&buf0[(4*q + 1) * 256 + 2 * n0]);
                float2 c2 = *(const float2*)(&buf0[(4*q + 2) * 256 + 2 * n0]);
                float2 c3 = *(const float2*)(&buf0[(4*q + 3) * 256 + 2 * n0]);
                sv[q] = make_float4(0.5f * (c0.x + c0.y), 0.5f * (c1.x + c1.y),
                                    0.5f * (c2.x + c2.y), 0.5f * (c3.x + c3.y));
            }
            const int xv = xs[31 + n0];
            float4 bpA, bpB; float hA, hB;
            halfmv(sA, &sBt[xv * BTS], sv, r0, bpA, bpB, hA, hB);
            const float pA = __shfl_xor(hA, 32, 64);
            const float pB = __shfl_xor(hB, 32, 64);
            const float nu = half ? (((pA + pB) + hA) + hB)
                                  : (((hA + hB) + pA) + pB);
            if (half == 0) ll += __logf(nu);
            const float inv = 1.f / nu;
            rr[0] = bpA.x * inv; rr[1] = bpA.y * inv;
            rr[2] = bpA.z * inv; rr[3] = bpA.w * inv;
            rr[4] = bpB.x * inv; rr[5] = bpB.y * inv;
            rr[6] = bpB.z * inv; rr[7] = bpB.w * inv;
        }

        // cnt2=16..1: children via __shfl, no LDS, no barriers.
        // UNGUARDED compute (all 64 lanes) so shfl sources stay in EXEC;
        // lanes n0>=cnt2 compute garbage that is never sourced later.
        #pragma unroll
        for (int cnt2 = 16; cnt2 >= 1; cnt2 >>= 1) {
            const int cl = 2 * n0;            // left-child node (valid for n0<cnt2)
            float4 sv[4];
            #pragma unroll
            for (int q = 0; q < 4; ++q) {
                float e[4];
                #pragma unroll
                for (int ei = 0; ei < 4; ++ei) {
                    const int j    = 4 * q + ei;    // row 0..15
                    const int slot = j & 7;
                    const int src  = ((j >> 3) * 32) + cl;
                    float a = __shfl(rr[slot], src,     64);  // child 2n0, row j
                    float b = __shfl(rr[slot], src + 1, 64);  // child 2n0+1, row j
                    e[ei] = 0.5f * (a + b);                   // same order as old (c.x+c.y)
                }
                sv[q] = make_float4(e[0], e[1], e[2], e[3]);
            }
            const int xv = xs[cnt2 - 1 + n0];  // in-bounds even for garbage lanes
            float4 bpA, bpB; float hA, hB;
            halfmv(sA, &sBt[xv * BTS], sv, r0, bpA, bpB, hA, hB);
            const float pA = __shfl_xor(hA, 32, 64);
            const float pB = __shfl_xor(hB, 32, 64);
            const float nu = half ? (((pA + pB) + hA) + hB)
                                  : (((hA + hB) + pA) + pB);
            if (half == 0 && n0 < cnt2) ll += __logf(nu);
            const float inv = 1.f / nu;
            rr[0] = bpA.x * inv; rr[1] = bpA.y * inv;
            rr[2] = bpA.z * inv; rr[3] = bpA.w * inv;
            rr[4] = bpB.x * inv; rr[5] = bpB.y * inv;
            rr[6] = bpB.z * inv; rr[7] = bpB.w * inv;
        }
    }

    // ---- reduce ll across block (wsum in buf0 row15 cols252-255) ----
    float v = ll;
    #pragma unroll
    for (int off = 32; off > 0; off >>= 1) v += __shfl_down(v, off, 64);
    if ((tid & 63) == 0) wsum[tid >> 6] = v;
    __syncthreads();
    if (tid == 0) out[t * G_DIM + g] = wsum[0] + wsum[1] + wsum[2] + wsum[3];
}

extern "C" void kernel_launch(void* const* d_in, const int* in_sizes, int n_in,
                              void* d_out, int out_size, void* d_ws, size_t ws_size,
                              hipStream_t stream) {
    const int*   x       = (const int*)d_in[0];
    const int*   inv_map = (const int*)d_in[6];
    const float* lA      = (const float*)d_in[7];
    const float* lB      = (const float*)d_in[8];
    const float* lPi     = (const float*)d_in[9];
    float* out = (float*)d_out;

    htmm_fused<<<dim3(NBLOCKS), dim3(256), 0, stream>>>(
        x, inv_map, lA, lB, lPi, out);
}

// Round 20
// 95.186 us; speedup vs baseline: 1.0689x; 1.0689x over previous
//
#include <hip/hip_runtime.h>

// UniformBottomUpHTMM: T=64 trees, depth 10 (N1=2047 heap), C=16, M=64,
// G=16. r31: PURE REVERT to r29 (champion: 94.7us headline, kernel ~29us).
// r30 post-mortem: dynamic-index __shfl on CDNA = ds_bpermute_b32 (LDS
// pipe, lgkm latency), NOT a VALU DPP op. The "register-resident" tail
// replaced 24 LDS ops/level with 32 bpermutes/level + a dependent chain
// through bpermute latency -> kernel ~29.5 -> ~36.5us. Only fixed-pattern
// shfl_xor maps to DPP; tree-child gathers are dynamic. Reverted.
// Current structure (r29): barrier-free blocks, one (t,g) each; linearity
// fold (tA tables kill all L9 matvecs); 2-wave hi/lo table phase; 4-wave
// L7 + 2-wave L6 hi/lo splits; LDS-based hi/lo tail; unfenced matvecs
// (VGPR ~96 < 128 cliff); 32KB LDS diet (5 blocks/CU capacity).
// Ledger of falsified levers: global-A staging (latency-bound), dual-node
// batching (VGPR), wave-autonomous quarters (redundant issue), lane-pair
// leaf (bank conflicts), shfl tail (bpermute). Remaining serial cost ~2us
// (tail) + grid-capped occupancy: at kernel ~29us vs ~9.5us VALU floor +
// ~12us LDS-issue floor, headroom is sub-noise.

#define C_DIM 16
#define M_DIM 64
#define G_DIM 16
#define T_TREES 64
#define N1 2047
#define NBLOCKS (T_TREES * G_DIM)   // 1024
#define BTS 20                      // padded row stride (floats) for xv-tables

__device__ __forceinline__ float4 f4add(float4 a, float4 b) {
    return make_float4(a.x + b.x, a.y + b.y, a.z + b.z, a.w + b.w);
}
__device__ __forceinline__ float4 f4mul(float4 a, float4 b) {
    return make_float4(a.x * b.x, a.y * b.y, a.z * b.z, a.w * b.w);
}
__device__ __forceinline__ float4 f4fma(float4 a, float4 b, float4 c) {
    return make_float4(fmaf(a.x, b.x, c.x), fmaf(a.y, b.y, c.y),
                       fmaf(a.z, b.z, c.z), fmaf(a.w, b.w, c.w));
}
__device__ __forceinline__ float hsum4(float4 a) { return a.x + a.y + a.z + a.w; }

// Full 16x16 matvec (leaf L8 only): unfenced (r29) -- loads may pipeline.
__device__ __forceinline__ float matvec_bt(const float* __restrict__ A,
                                           const float* __restrict__ bt,
                                           const float4 sv[4], float4 bp[4])
{
    float nu = 0.f;
    #pragma unroll
    for (int q = 0; q < 4; ++q) {
        const float4 b4 = *(const float4*)(bt + 4 * q);
        float tr[4];
        #pragma unroll
        for (int r = 0; r < 4; ++r) {
            const float4* ar = (const float4*)(A + (4 * q + r) * 16);
            float4 m = f4mul(ar[0], sv[0]);
            m = f4fma(ar[1], sv[1], m);
            m = f4fma(ar[2], sv[2], m);
            m = f4fma(ar[3], sv[3], m);
            tr[r] = hsum4(m);
        }
        bp[q] = f4mul(make_float4(tr[0], tr[1], tr[2], tr[3]), b4);
        nu += hsum4(bp[q]);
    }
    return nu;
}

// Half-matvec for the hi/lo split phases: rows r0..r0+7, unfenced.
__device__ __forceinline__ void halfmv(const float* __restrict__ A,
                                       const float* __restrict__ bt,
                                       const float4 sv[4], const int r0,
                                       float4& bpA, float4& bpB,
                                       float& hA, float& hB)
{
    float trA[4], trB[4];
    #pragma unroll
    for (int r = 0; r < 4; ++r) {
        const float4* ar = (const float4*)(A + (r0 + r) * 16);
        float4 m = f4mul(ar[0], sv[0]);
        m = f4fma(ar[1], sv[1], m);
        m = f4fma(ar[2], sv[2], m);
        m = f4fma(ar[3], sv[3], m);
        trA[r] = hsum4(m);
    }
    #pragma unroll
    for (int r = 0; r < 4; ++r) {
        const float4* ar = (const float4*)(A + (r0 + 4 + r) * 16);
        float4 m = f4mul(ar[0], sv[0]);
        m = f4fma(ar[1], sv[1], m);
        m = f4fma(ar[2], sv[2], m);
        m = f4fma(ar[3], sv[3], m);
        trB[r] = hsum4(m);
    }
    bpA = f4mul(make_float4(trA[0], trA[1], trA[2], trA[3]),
                *(const float4*)(bt + r0));
    bpB = f4mul(make_float4(trB[0], trB[1], trB[2], trB[3]),
                *(const float4*)(bt + r0 + 4));
    hA = hsum4(bpA);
    hB = hsum4(bpB);
}

__global__ __launch_bounds__(256, 1) void htmm_fused(
    const int* __restrict__ x,
    const int* __restrict__ inv_map,
    const float* __restrict__ lA,
    const float* __restrict__ lB,
    const float* __restrict__ lPi,
    float* __restrict__ out)
{
    const int bid = blockIdx.x;           // 1024 blocks: g = bid>>6, t = bid&63
    const int tid = threadIdx.x;
    const int g = bid >> 6;
    const int t = bid & (T_TREES - 1);

    // ---- manual LDS layout (r21 diet): 32768 B ----
    __shared__ __align__(16) unsigned char smem[32768];
    float* const sA   = (float*)(smem);            //     0 .. 1024   A row-major
    float* const sBt  = (float*)(smem + 1024);     //  1024 .. 6144   Bt[xv][c] stride 20
    float* const sPB  = (float*)(smem + 6144);     //  6144 .. 11264  tA[x]=A·PB[x] (leaf-phase only)
    float* const sLog = (float*)(smem + 11264);    // 11264 .. 11520  (dead after leaf)
    float* const sPi  = (float*)(smem + 11520);    // 11520 .. 11584  (dead after tables)
    float* const buf1 = (float*)(smem + 6144);     // UNION: live from L7 on (8192B)
    unsigned char* const xs = smem + 14336;        // 14336 .. 16384
    float* const buf0 = (float*)(smem + 16384);    // 16384 .. 32768
    float* const wsum = (float*)(smem + 32752);    // buf0 row15 col252-255 (tail-unused)

    // ---- tree symbols (coalesced; 16 same-tree blocks share L2) ----
    {
        const int base = t * N1;
        for (int i = tid; i < N1; i += 256)
            xs[i] = (unsigned char)x[inv_map[base + i]];
    }
    // ---- A softmax (over i within 16-lane segments) ----
    {
        int j = tid >> 4, i = tid & 15;
        float v = lA[(i * C_DIM + j) * G_DIM + g];
        float mx = v;
        #pragma unroll
        for (int m = 1; m < 16; m <<= 1) mx = fmaxf(mx, __shfl_xor(mx, m, 16));
        float e = __expf(v - mx);
        float s = e;
        #pragma unroll
        for (int m = 1; m < 16; m <<= 1) s += __shfl_xor(s, m, 16);
        sA[i * C_DIM + j] = e / s;
    }
    // ---- B softmax (over m), written TRANSPOSED: sBt[xv*BTS + c] ----
    {
        int c = tid >> 4, l16 = tid & 15;
        float e0 = lB[(c * M_DIM + l16 +  0) * G_DIM + g];
        float e1 = lB[(c * M_DIM + l16 + 16) * G_DIM + g];
        float e2 = lB[(c * M_DIM + l16 + 32) * G_DIM + g];
        float e3 = lB[(c * M_DIM + l16 + 48) * G_DIM + g];
        float mx = fmaxf(fmaxf(e0, e1), fmaxf(e2, e3));
        #pragma unroll
        for (int m = 1; m < 16; m <<= 1) mx = fmaxf(mx, __shfl_xor(mx, m, 16));
        e0 = __expf(e0 - mx); e1 = __expf(e1 - mx);
        e2 = __expf(e2 - mx); e3 = __expf(e3 - mx);
        float s = e0 + e1 + e2 + e3;
        #pragma unroll
        for (int m = 1; m < 16; m <<= 1) s += __shfl_xor(s, m, 16);
        float inv = 1.f / s;
        sBt[(l16 +  0) * BTS + c] = e0 * inv;
        sBt[(l16 + 16) * BTS + c] = e1 * inv;
        sBt[(l16 + 32) * BTS + c] = e2 * inv;
        sBt[(l16 + 48) * BTS + c] = e3 * inv;
    }
    if (tid < C_DIM) {  // Pi softmax
        float v = lPi[tid * G_DIM + g];
        float mx = v;
        #pragma unroll
        for (int m = 1; m < 16; m <<= 1) mx = fmaxf(mx, __shfl_xor(mx, m, 16));
        float e = __expf(v - mx);
        float s = e;
        #pragma unroll
        for (int m = 1; m < 16; m <<= 1) s += __shfl_xor(s, m, 16);
        sPi[tid] = e / s;
    }
    __syncthreads();

    // ---- leaf tables + LINEARITY fold on 2 WAVES, hi/lo split ----
    if (tid < 128) {
        const int w    = tid >> 6;            // wave 0..1
        const int half = (tid >> 5) & 1;      // 0: rows 0-7, 1: rows 8-15
        const int xv   = 32 * w + (tid & 31); // symbol 0..63
        float pb[16]; float nu = 0.f;
        #pragma unroll
        for (int k = 0; k < 16; ++k) {
            pb[k] = sPi[k] * sBt[xv * BTS + k];
            nu += pb[k];
        }
        const float inv = 0.5f / nu;
        #pragma unroll
        for (int k = 0; k < 16; ++k) pb[k] *= inv;
        if (half == 0) sLog[xv] = __logf(nu);
        const float4 pv0 = make_float4(pb[0],  pb[1],  pb[2],  pb[3]);
        const float4 pv1 = make_float4(pb[4],  pb[5],  pb[6],  pb[7]);
        const float4 pv2 = make_float4(pb[8],  pb[9],  pb[10], pb[11]);
        const float4 pv3 = make_float4(pb[12], pb[13], pb[14], pb[15]);
        const int r0 = half * 8;
        float ta[8];
        #pragma unroll
        for (int i = 0; i < 8; ++i) {
            const float4* ar = (const float4*)(sA + (r0 + i) * 16);
            float4 m = f4mul(ar[0], pv0);
            m = f4fma(ar[1], pv1, m);
            m = f4fma(ar[2], pv2, m);
            m = f4fma(ar[3], pv3, m);
            ta[i] = hsum4(m);
        }
        *(float4*)(&sPB[xv * BTS + r0])     = make_float4(ta[0], ta[1], ta[2], ta[3]);
        *(float4*)(&sPB[xv * BTS + r0 + 4]) = make_float4(ta[4], ta[5], ta[6], ta[7]);
    }
    __syncthreads();

    float ll = 0.f;

    // ---- fused leaves+L9 (TABLE, interleaved) + L8 matvec ----
    {
        const int idx = tid;
        const int p8  = 255 + idx;
        const int xl0 = xs[4 * p8 + 3], xr0 = xs[4 * p8 + 4];
        const int xl1 = xs[4 * p8 + 5], xr1 = xs[4 * p8 + 6];
        const int xva = xs[2 * p8 + 1], xvb = xs[2 * p8 + 2];
        const int xv8 = xs[p8];

        const float* tl0 = &sPB[xl0 * BTS];
        const float* tr0 = &sPB[xr0 * BTS];
        const float* tl1 = &sPB[xl1 * BTS];
        const float* tr1 = &sPB[xr1 * BTS];
        const float* bta = &sBt[xva * BTS];
        const float* btb = &sBt[xvb * BTS];

        float4 bpa[4], bpb[4];
        float nua = 0.f, nub = 0.f;
        #pragma unroll
        for (int q = 0; q < 4; ++q) {
            float4 tva = f4add(*(const float4*)(tl0 + 4*q),
                               *(const float4*)(tr0 + 4*q));
            float4 tvb = f4add(*(const float4*)(tl1 + 4*q),
                               *(const float4*)(tr1 + 4*q));
            bpa[q] = f4mul(tva, *(const float4*)(bta + 4*q));
            bpb[q] = f4mul(tvb, *(const float4*)(btb + 4*q));
            nua += hsum4(bpa[q]);
            nub += hsum4(bpb[q]);
        }
        const float ia = 0.5f / nua, ib = 0.5f / nub;
        float4 s8v[4];
        #pragma unroll
        for (int q = 0; q < 4; ++q)
            s8v[q] = f4add(f4mul(bpa[q], make_float4(ia, ia, ia, ia)),
                           f4mul(bpb[q], make_float4(ib, ib, ib, ib)));

        float4 bp[4];
        const float nu8 = matvec_bt(sA, &sBt[xv8 * BTS], s8v, bp);
        ll += sLog[xl0] + sLog[xr0] + sLog[xl1] + sLog[xr1]
            + __logf(nua * nub * nu8);
        const float inv = 1.f / nu8;
        #pragma unroll
        for (int q = 0; q < 4; ++q) {
            buf0[(4*q + 0) * 256 + idx] = bp[q].x * inv;
            buf0[(4*q + 1) * 256 + idx] = bp[q].y * inv;
            buf0[(4*q + 2) * 256 + idx] = bp[q].z * inv;
            buf0[(4*q + 3) * 256 + idx] = bp[q].w * inv;
        }
    }
    __syncthreads();

    // ---- L7: 128 nodes on ALL 4 waves, hi/lo split (unfenced) ----
    {
        const int w    = tid >> 6;            // wave 0..3
        const int half = (tid >> 5) & 1;      // 0: rows 0-7, 1: rows 8-15
        const int n    = 32 * w + (tid & 31); // node 0..127
        float4 sv[4];
        #pragma unroll
        for (int q = 0; q < 4; ++q) {
            float2 c0 = *(const float2*)(&buf0[(4*q + 0) * 256 + 2 * n]);
            float2 c1 = *(const float2*)(&buf0[(4*q + 1) * 256 + 2 * n]);
            float2 c2 = *(const float2*)(&buf0[(4*q + 2) * 256 + 2 * n]);
            float2 c3 = *(const float2*)(&buf0[(4*q + 3) * 256 + 2 * n]);
            sv[q] = make_float4(0.5f * (c0.x + c0.y), 0.5f * (c1.x + c1.y),
                                0.5f * (c2.x + c2.y), 0.5f * (c3.x + c3.y));
        }
        const int xv = xs[127 + n];
        const int r0 = half * 8;
        float4 bpA, bpB; float hA, hB;
        halfmv(sA, &sBt[xv * BTS], sv, r0, bpA, bpB, hA, hB);
        const float pA = __shfl_xor(hA, 32, 64);
        const float pB = __shfl_xor(hB, 32, 64);
        const float nu = half ? (((pA + pB) + hA) + hB)
                              : (((hA + hB) + pA) + pB);
        if (half == 0) ll += __logf(nu);
        const float inv = 1.f / nu;
        buf1[(r0 + 0) * 128 + n] = bpA.x * inv;
        buf1[(r0 + 1) * 128 + n] = bpA.y * inv;
        buf1[(r0 + 2) * 128 + n] = bpA.z * inv;
        buf1[(r0 + 3) * 128 + n] = bpA.w * inv;
        buf1[(r0 + 4) * 128 + n] = bpB.x * inv;
        buf1[(r0 + 5) * 128 + n] = bpB.y * inv;
        buf1[(r0 + 6) * 128 + n] = bpB.z * inv;
        buf1[(r0 + 7) * 128 + n] = bpB.w * inv;
    }
    __syncthreads();

    // ---- L6: 64 nodes on 2 waves, hi/lo split (unfenced) ----
    if (tid < 128) {
        const int w    = tid >> 6;            // wave 0..1
        const int half = (tid >> 5) & 1;
        const int n    = 32 * w + (tid & 31); // node 0..63
        float4 sv[4];
        #pragma unroll
        for (int q = 0; q < 4; ++q) {
            float2 c0 = *(const float2*)(&buf1[(4*q + 0) * 128 + 2 * n]);
            float2 c1 = *(const float2*)(&buf1[(4*q + 1) * 128 + 2 * n]);
            float2 c2 = *(const float2*)(&buf1[(4*q + 2) * 128 + 2 * n]);
            float2 c3 = *(const float2*)(&buf1[(4*q + 3) * 128 + 2 * n]);
            sv[q] = make_float4(0.5f * (c0.x + c0.y), 0.5f * (c1.x + c1.y),
                                0.5f * (c2.x + c2.y), 0.5f * (c3.x + c3.y));
        }
        const int xv = xs[63 + n];
        const int r0 = half * 8;
        float4 bpA, bpB; float hA, hB;
        halfmv(sA, &sBt[xv * BTS], sv, r0, bpA, bpB, hA, hB);
        const float pA = __shfl_xor(hA, 32, 64);
        const float pB = __shfl_xor(hB, 32, 64);
        const float nu = half ? (((pA + pB) + hA) + hB)
                              : (((hA + hB) + pA) + pB);
        if (half == 0) ll += __logf(nu);
        const float inv = 1.f / nu;
        buf0[(r0 + 0) * 256 + n] = bpA.x * inv;
        buf0[(r0 + 1) * 256 + n] = bpA.y * inv;
        buf0[(r0 + 2) * 256 + n] = bpA.z * inv;
        buf0[(r0 + 3) * 256 + n] = bpA.w * inv;
        buf0[(r0 + 4) * 256 + n] = bpB.x * inv;
        buf0[(r0 + 5) * 256 + n] = bpB.y * inv;
        buf0[(r0 + 6) * 256 + n] = bpB.z * inv;
        buf0[(r0 + 7) * 256 + n] = bpB.w * inv;
    }
    __syncthreads();

    // ---- tail L5..L0 (cnt2=32..1): wave 0, hi/lo split, unfenced ----
    if (tid < 64) {
        float* cur = buf0; int cs = 256;
        float* nxt = buf1; int ns = 128;
        for (int cnt2 = 32; cnt2 >= 1; cnt2 >>= 1) {
            const int half = tid >> 5;
            const int n    = tid & 31;
            if (n < cnt2) {
                float4 sv[4];
                #pragma unroll
                for (int q = 0; q < 4; ++q) {
                    float2 c0 = *(const float2*)(&cur[(4*q + 0) * cs + 2 * n]);
                    float2 c1 = *(const float2*)(&cur[(4*q + 1) * cs + 2 * n]);
                    float2 c2 = *(const float2*)(&cur[(4*q + 2) * cs + 2 * n]);
                    float2 c3 = *(const float2*)(&cur[(4*q + 3) * cs + 2 * n]);
                    sv[q] = make_float4(0.5f * (c0.x + c0.y), 0.5f * (c1.x + c1.y),
                                        0.5f * (c2.x + c2.y), 0.5f * (c3.x + c3.y));
                }
                const int xv = xs[cnt2 - 1 + n];
                const int r0 = half * 8;
                float4 bpA, bpB; float hA, hB;
                halfmv(sA, &sBt[xv * BTS], sv, r0, bpA, bpB, hA, hB);
                const float pA = __shfl_xor(hA, 32, 64);
                const float pB = __shfl_xor(hB, 32, 64);
                const float nu = half ? (((pA + pB) + hA) + hB)
                                      : (((hA + hB) + pA) + pB);
                if (half == 0) ll += __logf(nu);
                const float inv = 1.f / nu;
                nxt[(r0 + 0) * ns + n] = bpA.x * inv;
                nxt[(r0 + 1) * ns + n] = bpA.y * inv;
                nxt[(r0 + 2) * ns + n] = bpA.z * inv;
                nxt[(r0 + 3) * ns + n] = bpA.w * inv;
                nxt[(r0 + 4) * ns + n] = bpB.x * inv;
                nxt[(r0 + 5) * ns + n] = bpB.y * inv;
                nxt[(r0 + 6) * ns + n] = bpB.z * inv;
                nxt[(r0 + 7) * ns + n] = bpB.w * inv;
            }
            asm volatile("s_waitcnt lgkmcnt(0)" ::: "memory");
            __builtin_amdgcn_wave_barrier();
            float* tp = cur; cur = nxt; nxt = tp;
            int ts = cs; cs = ns; ns = ts;
        }
    }

    // ---- reduce ll across block (wsum in buf0 row15 cols252-255) ----
    float v = ll;
    #pragma unroll
    for (int off = 32; off > 0; off >>= 1) v += __shfl_down(v, off, 64);
    if ((tid & 63) == 0) wsum[tid >> 6] = v;
    __syncthreads();
    if (tid == 0) out[t * G_DIM + g] = wsum[0] + wsum[1] + wsum[2] + wsum[3];
}

extern "C" void kernel_launch(void* const* d_in, const int* in_sizes, int n_in,
                              void* d_out, int out_size, void* d_ws, size_t ws_size,
                              hipStream_t stream) {
    const int*   x       = (const int*)d_in[0];
    const int*   inv_map = (const int*)d_in[6];
    const float* lA      = (const float*)d_in[7];
    const float* lB      = (const float*)d_in[8];
    const float* lPi     = (const float*)d_in[9];
    float* out = (float*)d_out;

    htmm_fused<<<dim3(NBLOCKS), dim3(256), 0, stream>>>(
        x, inv_map, lA, lB, lPi, out);
}